// Round 14
// baseline (587.968 us; speedup 1.0000x reference)
//
#include <hip/hip_runtime.h>

typedef __attribute__((ext_vector_type(8))) short s16x8;
typedef __attribute__((ext_vector_type(8))) __bf16 bf16x8;
typedef __attribute__((ext_vector_type(4))) float f32x4;

#define S_LEN 2048
#define KDIM  4096
// softmax scale * log2(e): (1/sqrt(128)) * 1.4426950408889634
#define CSOFT 0.12751743f

__device__ __forceinline__ unsigned short f2bf(float f) {
  unsigned u = __builtin_bit_cast(unsigned, f);
  u += 0x7fffu + ((u >> 16) & 1u);
  return (unsigned short)(u >> 16);
}

__device__ __forceinline__ f32x4 mfma_bf16(s16x8 a, s16x8 b, f32x4 c) {
  return __builtin_amdgcn_mfma_f32_16x16x32_bf16(
      __builtin_bit_cast(bf16x8, a), __builtin_bit_cast(bf16x8, b), c, 0, 0, 0);
}

// async global->LDS, 16B per lane. lds ptr must be wave-uniform; g is per-lane.
__device__ __forceinline__ void gload_lds16(const unsigned short* g, void* l) {
  __builtin_amdgcn_global_load_lds(
      (const __attribute__((address_space(1))) void*)g,
      (__attribute__((address_space(3))) void*)l, 16, 0, 0);
}

__device__ __forceinline__ void cvt8(const float* p, unsigned short* out) {
  f32x4 a = *(const f32x4*)(p);
  f32x4 b = *(const f32x4*)(p + 4);
  s16x8 v;
  v[0] = (short)f2bf(a[0]); v[1] = (short)f2bf(a[1]);
  v[2] = (short)f2bf(a[2]); v[3] = (short)f2bf(a[3]);
  v[4] = (short)f2bf(b[0]); v[5] = (short)f2bf(b[1]);
  v[6] = (short)f2bf(b[2]); v[7] = (short)f2bf(b[3]);
  *(s16x8*)(out) = v;
}

// ---------------- fp32 -> bf16 convert (fallback path) ----------------
__global__ void cvt_bf16(const float* __restrict__ in,
                         unsigned short* __restrict__ out, int n8) {
  int i = blockIdx.x * 256 + threadIdx.x;
  if (i >= n8) return;
  cvt8(in + (size_t)i * 8, out + (size_t)i * 8);
}

// fused 5-array convert, grid-stride over 28672 logical chunks:
// x 8192 | wq 8192 | wk 2048 | wv 2048 | wo 8192
__global__ void cvt_all(const float* __restrict__ x, const float* __restrict__ wq,
                        const float* __restrict__ wk, const float* __restrict__ wv,
                        const float* __restrict__ wo,
                        unsigned short* __restrict__ ox, unsigned short* __restrict__ oq,
                        unsigned short* __restrict__ ok, unsigned short* __restrict__ ov,
                        unsigned short* __restrict__ oo) {
  for (int blk = blockIdx.x; blk < 28672; blk += 2048) {
    const float* src;
    unsigned short* dst;
    int i;
    if (blk < 8192) { src = x; dst = ox; i = blk; }
    else if (blk < 16384) { src = wq; dst = oq; i = blk - 8192; }
    else if (blk < 18432) { src = wk; dst = ok; i = blk - 16384; }
    else if (blk < 20480) { src = wv; dst = ov; i = blk - 18432; }
    else { src = wo; dst = oo; i = blk - 20480; }
    size_t idx = ((size_t)i * 256 + threadIdx.x) * 8;
    cvt8(src + idx, dst + idx);
  }
}

// ====== 256x256 BK=64 8-wave pipelined GEMM, 3-phase/tile (6 barriers) ====
// XCD-locality: each XCD gets a 4rt x 8ct tile cluster.
// FROZEN at R11-best: 6 schedule variants (vmcnt depth 1-5, phase 3/4/8,
// asm ds_read) all land 31-33.5% MfmaUtil; do not re-enter.
template <int EPI>
__global__ __launch_bounds__(512, 1)
void gemm256(const unsigned short* __restrict__ A,
             const unsigned short* __restrict__ B,
             void* __restrict__ Out,
             const float* __restrict__ cosT,
             const float* __restrict__ sinT) {
  const int K = KDIM;
  __shared__ __align__(16) unsigned short As[2 * 2 * 8192];
  __shared__ __align__(16) unsigned short Bs[2 * 2 * 8192];

  const int tid = threadIdx.x;
  const int lane = tid & 63, wid = tid >> 6;
  const int l15 = lane & 15, l4 = lane >> 4;
  const int wr = wid >> 2, wc = wid & 3;

  int bid = blockIdx.x;
  const int xcd = bid & 7, ii = bid >> 3;
  const int rt = (xcd >> 1) * 4 + (ii >> 3);
  const int ct = (xcd & 1) * 8 + (ii & 7);
  const int row0 = rt * 256, col0 = ct * 256;

  const int ch0 = tid, ch1 = 512 + tid;
  const int sr0 = ch0 >> 3, u0 = (ch0 & 7) ^ (sr0 & 7);
  const int sr1 = ch1 >> 3, u1 = (ch1 & 7) ^ (sr1 & 7);
  const unsigned short* A0p = A + (size_t)(row0 + sr0) * K + u0 * 8;
  const unsigned short* A1p = A + (size_t)(row0 + sr1) * K + u1 * 8;
  const unsigned short* B0p = B + (size_t)(col0 + sr0) * K + u0 * 8;
  const unsigned short* B1p = B + (size_t)(col0 + sr1) * K + u1 * 8;

  const int rdo0 = l15 * 128 + ((l4 ^ (l15 & 7)) << 4);
  const int rdo1 = l15 * 128 + (((4 | l4) ^ (l15 & 7)) << 4);

  f32x4 acc[8][4];
#pragma unroll
  for (int m = 0; m < 8; m++)
#pragma unroll
    for (int n = 0; n < 4; n++) acc[m][n] = f32x4{0.f, 0.f, 0.f, 0.f};

  auto stageA = [&](int buf, int h, int kt) {
    char* d = (char*)As + buf * 32768 + h * 16384 + wid * 1024;
    size_t so = (size_t)h * 128 * K + kt;
    gload_lds16(A0p + so, d);
    gload_lds16(A1p + so, d + 8192);
  };
  auto stageB = [&](int buf, int h, int kt) {
    char* d = (char*)Bs + buf * 32768 + h * 16384 + wid * 1024;
    size_t so = (size_t)h * 128 * K + kt;
    gload_lds16(B0p + so, d);
    gload_lds16(B1p + so, d + 8192);
  };
  auto bar = [&]() { __builtin_amdgcn_s_barrier(); };
  auto quad = [&](const s16x8* ak0, const s16x8* ak1,
                  const s16x8* bk0, const s16x8* bk1, int mb, int nb) {
    __builtin_amdgcn_s_setprio(1);
#pragma unroll
    for (int mi = 0; mi < 4; mi++)
#pragma unroll
      for (int ni = 0; ni < 2; ni++) {
        acc[mb + mi][nb + ni] =
            mfma_bf16(ak0[mi], bk0[ni], acc[mb + mi][nb + ni]);
        acc[mb + mi][nb + ni] =
            mfma_bf16(ak1[mi], bk1[ni], acc[mb + mi][nb + ni]);
      }
    __builtin_amdgcn_s_setprio(0);
  };

  auto tile3 = [&](int buf, auto st1, auto st2, auto st3, int vmEnd) {
    const char* Ab = (const char*)As + buf * 32768 + wr * 16384;
    const char* Bb = (const char*)Bs + buf * 32768 + (wc >> 1) * 16384 +
                     (wc & 1) * 8192;
    s16x8 a0k0[4], a0k1[4], a1k0[4], a1k1[4];
    s16x8 b0k0[2], b0k1[2], b1k0[2], b1k1[2];

#pragma unroll
    for (int mi = 0; mi < 4; mi++) {
      a0k0[mi] = *(const s16x8*)(Ab + mi * 2048 + rdo0);
      a0k1[mi] = *(const s16x8*)(Ab + mi * 2048 + rdo1);
    }
#pragma unroll
    for (int ni = 0; ni < 2; ni++) {
      b0k0[ni] = *(const s16x8*)(Bb + ni * 2048 + rdo0);
      b0k1[ni] = *(const s16x8*)(Bb + ni * 2048 + rdo1);
    }
    st1();
    bar();
    quad(a0k0, a0k1, b0k0, b0k1, 0, 0);
    bar();

#pragma unroll
    for (int mi = 0; mi < 4; mi++) {
      a1k0[mi] = *(const s16x8*)(Ab + 8192 + mi * 2048 + rdo0);
      a1k1[mi] = *(const s16x8*)(Ab + 8192 + mi * 2048 + rdo1);
    }
    st2();
    bar();
    quad(a1k0, a1k1, b0k0, b0k1, 4, 0);
    bar();

#pragma unroll
    for (int ni = 0; ni < 2; ni++) {
      b1k0[ni] = *(const s16x8*)(Bb + 4096 + ni * 2048 + rdo0);
      b1k1[ni] = *(const s16x8*)(Bb + 4096 + ni * 2048 + rdo1);
    }
    st3();
    bar();
    quad(a0k0, a0k1, b1k0, b1k1, 0, 2);
    quad(a1k0, a1k1, b1k0, b1k1, 4, 2);
    if (vmEnd == 4) {
      asm volatile("s_waitcnt vmcnt(4)" ::: "memory");
    } else if (vmEnd == 0) {
      asm volatile("s_waitcnt vmcnt(0)" ::: "memory");
    }
    bar();
  };
  auto nop = [&]() {};

  stageA(0, 0, 0);
  stageA(0, 1, 0);
  stageB(0, 0, 0);
  stageB(0, 1, 0);
  stageA(1, 0, 64);
  stageA(1, 1, 64);
  asm volatile("s_waitcnt vmcnt(4)" ::: "memory");
  bar();

  for (int j = 0; j < 31; j++) {
    const int k1 = (2 * j + 1) * 64, k2 = (2 * j + 2) * 64,
              k3 = (2 * j + 3) * 64;
    tile3(0, [&] { stageB(1, 0, k1); }, [&] { stageB(1, 1, k1); },
          [&] { stageA(0, 0, k2); stageA(0, 1, k2); }, 4);
    tile3(1, [&] { stageB(0, 0, k2); }, [&] { stageB(0, 1, k2); },
          [&] { stageA(1, 0, k3); stageA(1, 1, k3); }, 4);
  }
  {
    const int k1 = 63 * 64;
    tile3(0, [&] { stageB(1, 0, k1); }, [&] { stageB(1, 1, k1); }, nop, 0);
    tile3(1, nop, nop, nop, -1);
  }

  // ---- epilogue ----
#pragma unroll
  for (int m = 0; m < 8; m++) {
#pragma unroll
    for (int n = 0; n < 4; n++) {
      f32x4 v = acc[m][n];
      int rowb = row0 + wr * 128 + m * 16 + l4 * 4;
      int col = col0 + wc * 64 + n * 16 + l15;
      if (EPI == 3) {
        float* o = (float*)Out;
#pragma unroll
        for (int r = 0; r < 4; r++) o[(size_t)(rowb + r) * 4096 + col] = v[r];
      } else {
        float vp[4];
#pragma unroll
        for (int r = 0; r < 4; r++) vp[r] = __shfl_xor(v[r], 1, 64);
        bool odd = lane & 1;
        int fi = (col & 127) >> 1;
#pragma unroll
        for (int r = 0; r < 4; r++) {
          int nn = rowb + r, s = nn >> 1;
          float c = cosT[s * 64 + fi], sn = sinT[s * 64 + fi];
          v[r] = odd ? (vp[r] * sn + v[r] * c) : (v[r] * c - vp[r] * sn);
        }
        unsigned short* o = (unsigned short*)Out;
        int hh = col >> 7, hd = col & 127;
#pragma unroll
        for (int r = 0; r < 4; r++) {
          int nn = rowb + r, s = nn >> 1, b = nn & 1;
          o[((size_t)(b * 32 + hh) * 2048 + s) * 128 + hd] = f2bf(v[r]);
        }
      }
    }
  }
}

// ====== merged K+V projection GEMM: 512 blocks, N=1024 each ======
// bid<256: K-task (RoPE, store [b][8][s][hd]); else V-task (store [b][8][hd][s])
// VGPR live set ~60 <= 128 cap at 4 waves/SIMD -> (256,4) is spill-free.
__global__ __launch_bounds__(256, 4)
void gemm_kv(const unsigned short* __restrict__ A,
             const unsigned short* __restrict__ Bk,
             const unsigned short* __restrict__ Bv,
             unsigned short* __restrict__ OutK,
             unsigned short* __restrict__ OutV,
             const float* __restrict__ cosT,
             const float* __restrict__ sinT) {
  const int K = KDIM;
  const int tid = threadIdx.x;
  const int lane = tid & 63, wid = tid >> 6;
  const int l15 = lane & 15, l4 = lane >> 4;
  const bool isV = blockIdx.x >= 256;
  const int lb = blockIdx.x & 255;
  const int ct = lb & 7, rt = lb >> 3;
  const int row0 = rt * 128, col0 = ct * 128;
  const int wr = wid >> 1, wc = wid & 1;
  const unsigned short* Bw = isV ? Bv : Bk;

  __shared__ __align__(16) unsigned short As[128 * 32];
  __shared__ __align__(16) unsigned short Bs[128 * 32];

  f32x4 acc[4][4];
#pragma unroll
  for (int i = 0; i < 4; i++)
#pragma unroll
    for (int j = 0; j < 4; j++) acc[i][j] = f32x4{0.f, 0.f, 0.f, 0.f};

  for (int kt = 0; kt < K; kt += 32) {
#pragma unroll
    for (int i = 0; i < 2; i++) {
      int j = wid * 2 + i;
      int ch = j * 64 + lane;
      int r = ch >> 2, c = ch & 3;
      int sc = c ^ ((r >> 1) & 3);
      gload_lds16(A + (size_t)(row0 + r) * K + kt + sc * 8, (char*)As + j * 1024);
      gload_lds16(Bw + (size_t)(col0 + r) * K + kt + sc * 8, (char*)Bs + j * 1024);
    }
    __syncthreads();

    s16x8 af[4], bfr[4];
#pragma unroll
    for (int mi = 0; mi < 4; mi++) {
      int r = wr * 64 + mi * 16 + l15;
      int sw = l4 ^ ((r >> 1) & 3);
      af[mi] = *(const s16x8*)((char*)As + r * 64 + sw * 16);
    }
#pragma unroll
    for (int ni = 0; ni < 4; ni++) {
      int r = wc * 64 + ni * 16 + l15;
      int sw = l4 ^ ((r >> 1) & 3);
      bfr[ni] = *(const s16x8*)((char*)Bs + r * 64 + sw * 16);
    }
#pragma unroll
    for (int mi = 0; mi < 4; mi++)
#pragma unroll
      for (int ni = 0; ni < 4; ni++)
        acc[mi][ni] = mfma_bf16(af[mi], bfr[ni], acc[mi][ni]);
    __syncthreads();
  }

#pragma unroll
  for (int mi = 0; mi < 4; mi++) {
#pragma unroll
    for (int ni = 0; ni < 4; ni++) {
      f32x4 v = acc[mi][ni];
      int rowb = row0 + wr * 64 + mi * 16 + l4 * 4;
      int col = col0 + wc * 64 + ni * 16 + l15;
      if (!isV) {  // RoPE for K
        float vp[4];
#pragma unroll
        for (int r = 0; r < 4; r++) vp[r] = __shfl_xor(v[r], 1, 64);
        bool odd = lane & 1;
        int fi = (col & 127) >> 1;
#pragma unroll
        for (int r = 0; r < 4; r++) {
          int n = rowb + r, s = n >> 1;
          float c = cosT[s * 64 + fi], sn = sinT[s * 64 + fi];
          v[r] = odd ? (vp[r] * sn + v[r] * c) : (v[r] * c - vp[r] * sn);
        }
        int hh = col >> 7, hd = col & 127;
#pragma unroll
        for (int r = 0; r < 4; r++) {
          int n = rowb + r, s = n >> 1, b = n & 1;
          OutK[((size_t)(b * 8 + hh) * 2048 + s) * 128 + hd] = f2bf(v[r]);
        }
      } else {
        int hh = col >> 7, hd = col & 127;
#pragma unroll
        for (int r = 0; r < 4; r++) {
          int n = rowb + r, s = n >> 1, b = n & 1;
          OutV[((size_t)(b * 8 + hh) * 128 + hd) * 2048 + s] = f2bf(v[r]);
        }
      }
    }
  }
}

// ---------------- GEMM: fallback-path template ----------------
template <int EPI, int N, bool B_FP32>
__global__ __launch_bounds__(256, 2)
void gemm_bt(const unsigned short* __restrict__ A,
             const float* __restrict__ Bw32,
             const unsigned short* __restrict__ Bw16,
             void* __restrict__ Out,
             const float* __restrict__ cosT,
             const float* __restrict__ sinT) {
  const int K = KDIM;
  const int tid = threadIdx.x;
  const int lane = tid & 63, wid = tid >> 6;
  const int l15 = lane & 15, l4 = lane >> 4;
  const int nct = N / 128;
  const int ct = blockIdx.x % nct, rt = blockIdx.x / nct;
  const int row0 = rt * 128, col0 = ct * 128;
  const int wr = wid >> 1, wc = wid & 1;

  __shared__ __align__(16) unsigned short As[128 * 32];
  __shared__ __align__(16) unsigned short Bs[128 * 32];

  f32x4 acc[4][4];
#pragma unroll
  for (int i = 0; i < 4; i++)
#pragma unroll
    for (int j = 0; j < 4; j++) acc[i][j] = f32x4{0.f, 0.f, 0.f, 0.f};

  for (int kt = 0; kt < K; kt += 32) {
#pragma unroll
    for (int i = 0; i < 2; i++) {
      int j = wid * 2 + i;
      int ch = j * 64 + lane;
      int r = ch >> 2, c = ch & 3;
      int sc = c ^ ((r >> 1) & 3);
      gload_lds16(A + (size_t)(row0 + r) * K + kt + sc * 8, (char*)As + j * 1024);
    }
    if (B_FP32) {
#pragma unroll
      for (int j = 0; j < 2; j++) {
        int ch = tid + 256 * j;
        int r = ch >> 2, c = ch & 3;
        const float* src = Bw32 + (size_t)(col0 + r) * K + kt + c * 8;
        f32x4 f0 = *(const f32x4*)(src);
        f32x4 f1 = *(const f32x4*)(src + 4);
        s16x8 v;
        v[0] = (short)f2bf(f0[0]); v[1] = (short)f2bf(f0[1]);
        v[2] = (short)f2bf(f0[2]); v[3] = (short)f2bf(f0[3]);
        v[4] = (short)f2bf(f1[0]); v[5] = (short)f2bf(f1[1]);
        v[6] = (short)f2bf(f1[2]); v[7] = (short)f2bf(f1[3]);
        int sw = c ^ ((r >> 1) & 3);
        *(s16x8*)((char*)Bs + r * 64 + sw * 16) = v;
      }
    } else {
#pragma unroll
      for (int i = 0; i < 2; i++) {
        int j = wid * 2 + i;
        int ch = j * 64 + lane;
        int r = ch >> 2, c = ch & 3;
        int sc = c ^ ((r >> 1) & 3);
        gload_lds16(Bw16 + (size_t)(col0 + r) * K + kt + sc * 8, (char*)Bs + j * 1024);
      }
    }
    __syncthreads();

    s16x8 af[4], bfr[4];
#pragma unroll
    for (int mi = 0; mi < 4; mi++) {
      int r = wr * 64 + mi * 16 + l15;
      int sw = l4 ^ ((r >> 1) & 3);
      af[mi] = *(const s16x8*)((char*)As + r * 64 + sw * 16);
    }
#pragma unroll
    for (int ni = 0; ni < 4; ni++) {
      int r = wc * 64 + ni * 16 + l15;
      int sw = l4 ^ ((r >> 1) & 3);
      bfr[ni] = *(const s16x8*)((char*)Bs + r * 64 + sw * 16);
    }
#pragma unroll
    for (int mi = 0; mi < 4; mi++)
#pragma unroll
      for (int ni = 0; ni < 4; ni++)
        acc[mi][ni] = mfma_bf16(af[mi], bfr[ni], acc[mi][ni]);
    __syncthreads();
  }

#pragma unroll
  for (int mi = 0; mi < 4; mi++) {
#pragma unroll
    for (int ni = 0; ni < 4; ni++) {
      f32x4 v = acc[mi][ni];
      int rowb = row0 + wr * 64 + mi * 16 + l4 * 4;
      int col = col0 + wc * 64 + ni * 16 + l15;
      if (EPI == 3) {
        float* o = (float*)Out;
#pragma unroll
        for (int r = 0; r < 4; r++) o[(size_t)(rowb + r) * 4096 + col] = v[r];
      } else {
        if (EPI != 2) {
          float vp[4];
#pragma unroll
          for (int r = 0; r < 4; r++) vp[r] = __shfl_xor(v[r], 1, 64);
          bool odd = lane & 1;
          int fi = (col & 127) >> 1;
#pragma unroll
          for (int r = 0; r < 4; r++) {
            int n = rowb + r, s = n >> 1;
            float c = cosT[s * 64 + fi], sn = sinT[s * 64 + fi];
            v[r] = odd ? (vp[r] * sn + v[r] * c) : (v[r] * c - vp[r] * sn);
          }
        }
        unsigned short* o = (unsigned short*)Out;
        int hh = col >> 7, hd = col & 127;
#pragma unroll
        for (int r = 0; r < 4; r++) {
          int n = rowb + r, s = n >> 1, b = n & 1;
          size_t idx;
          if (EPI == 0)      idx = ((size_t)(b * 32 + hh) * 2048 + s) * 128 + hd;
          else if (EPI == 1) idx = ((size_t)(b * 8 + hh) * 2048 + s) * 128 + hd;
          else               idx = ((size_t)(b * 8 + hh) * 128 + hd) * 2048 + s;
          o[idx] = f2bf(v[r]);
        }
      }
    }
  }
}

// ---------------- Flash attention (causal, GQA) — R11-exact (171us best) ---
__global__ __launch_bounds__(256, 2)
void attn_fwd(const unsigned short* __restrict__ Qa,
              const unsigned short* __restrict__ Ka,
              const unsigned short* __restrict__ Vt,
              unsigned short* __restrict__ AO) {
  int bid = blockIdx.x;
  int xcd = bid & 7, slot = bid >> 3;
  int grp = xcd + 8 * (slot >> 5);
  int idx = slot & 31;
  int b = grp >> 3, kvh = grp & 7;
  int pid = idx & 7;
  int h = kvh * 4 + ((idx >> 3) & 3);
  int tid = threadIdx.x, lane = tid & 63, wid = tid >> 6;
  int l15 = lane & 15, l4 = lane >> 4;

  __shared__ __align__(16) unsigned short Ks[64 * 128];
  __shared__ __align__(16) unsigned short Vs[128 * 64];
  __shared__ __align__(16) unsigned short Ps[4][32 * 64];

  const unsigned short* Qp = Qa + ((size_t)(b * 32 + h) * 2048) * 128;
  const unsigned short* Kp = Ka + ((size_t)(b * 8 + kvh) * 2048) * 128;
  const unsigned short* Vp = Vt + ((size_t)(b * 8 + kvh) * 128) * 2048;

  for (int half = 0; half < 2; half++) {
    int qt = half == 0 ? (7 - pid) : (8 + pid);
    int q0 = qt * 128, qr0 = q0 + wid * 32;

    s16x8 qf[2][4];
#pragma unroll
    for (int mi = 0; mi < 2; mi++)
#pragma unroll
      for (int ks = 0; ks < 4; ks++)
        qf[mi][ks] = *(const s16x8*)(Qp + (size_t)(qr0 + mi * 16 + l15) * 128 +
                                     ks * 32 + l4 * 8);

    f32x4 o[2][8];
#pragma unroll
    for (int mi = 0; mi < 2; mi++)
#pragma unroll
      for (int nb = 0; nb < 8; nb++) o[mi][nb] = f32x4{0.f, 0.f, 0.f, 0.f};
    float m[2][4], lsum[2][4];
#pragma unroll
    for (int mi = 0; mi < 2; mi++)
#pragma unroll
      for (int pr = 0; pr < 4; pr++) { m[mi][pr] = -1e30f; lsum[mi][pr] = 0.f; }

    int nt = q0 / 64 + 2;
    for (int t = 0; t < nt; t++) {
      int s0 = t * 64;
      const unsigned short* ktp = Kp + (size_t)s0 * 128;
#pragma unroll
      for (int i = 0; i < 4; i++) {
        int j = wid * 4 + i;
        int ch = j * 64 + lane;
        {
          int r = ch >> 4, cl = ch & 15;
          int sc = (cl & 8) | ((cl ^ (r & 7)) & 7);
          gload_lds16(ktp + r * 128 + sc * 8, (char*)Ks + j * 1024);
        }
        {
          int r = ch >> 3, p = ch & 7;
          int sc = p ^ (r & 7);
          gload_lds16(Vp + (size_t)r * 2048 + s0 + sc * 8, (char*)Vs + j * 1024);
        }
      }
      __syncthreads();

      if (s0 <= qr0 + 31) {
        f32x4 sc[2][4];
#pragma unroll
        for (int mi = 0; mi < 2; mi++)
#pragma unroll
          for (int kb = 0; kb < 4; kb++) sc[mi][kb] = f32x4{0.f, 0.f, 0.f, 0.f};
        __builtin_amdgcn_s_setprio(1);
#pragma unroll
        for (int kb = 0; kb < 4; kb++) {
          int r = kb * 16 + l15;
#pragma unroll
          for (int ks = 0; ks < 4; ks++) {
            int c = ks * 4 + l4;
            int sw = (c & 8) | ((c ^ (r & 7)) & 7);
            s16x8 kf = *(const s16x8*)((char*)Ks + r * 256 + sw * 16);
            sc[0][kb] = mfma_bf16(qf[0][ks], kf, sc[0][kb]);
            sc[1][kb] = mfma_bf16(qf[1][ks], kf, sc[1][kb]);
          }
        }
        __builtin_amdgcn_s_setprio(0);
        bool needmask = (s0 + 63) > qr0;
#pragma unroll
        for (int mi = 0; mi < 2; mi++) {
          if (needmask) {
#pragma unroll
            for (int kb = 0; kb < 4; kb++) {
              int kg = s0 + kb * 16 + l15;
#pragma unroll
              for (int pr = 0; pr < 4; pr++) {
                int qg = qr0 + mi * 16 + l4 * 4 + pr;
                if (kg > qg) sc[mi][kb][pr] = -1e30f;
              }
            }
          }
          float rm[4];
#pragma unroll
          for (int pr = 0; pr < 4; pr++)
            rm[pr] = fmaxf(fmaxf(sc[mi][0][pr], sc[mi][1][pr]),
                           fmaxf(sc[mi][2][pr], sc[mi][3][pr]));
#pragma unroll
          for (int xm = 1; xm <= 8; xm <<= 1)
#pragma unroll
            for (int pr = 0; pr < 4; pr++)
              rm[pr] = fmaxf(rm[pr], __shfl_xor(rm[pr], xm, 64));
          bool grow = false;
#pragma unroll
          for (int pr = 0; pr < 4; pr++)
            grow = grow || ((rm[pr] - m[mi][pr]) * CSOFT > 8.f);
          if (__any(grow)) {
            float fac[4];
#pragma unroll
            for (int pr = 0; pr < 4; pr++) {
              float nm = fmaxf(m[mi][pr], rm[pr]);
              fac[pr] = __builtin_amdgcn_exp2f((m[mi][pr] - nm) * CSOFT);
              m[mi][pr] = nm;
              lsum[mi][pr] *= fac[pr];
            }
#pragma unroll
            for (int nb = 0; nb < 8; nb++)
#pragma unroll
              for (int pr = 0; pr < 4; pr++) o[mi][nb][pr] *= fac[pr];
          }
          float rs[4] = {0.f, 0.f, 0.f, 0.f};
#pragma unroll
          for (int kb = 0; kb < 4; kb++)
#pragma unroll
            for (int pr = 0; pr < 4; pr++) {
              float p = __builtin_amdgcn_exp2f((sc[mi][kb][pr] - m[mi][pr]) * CSOFT);
              sc[mi][kb][pr] = p;
              rs[pr] += p;
            }
#pragma unroll
          for (int xm = 1; xm <= 8; xm <<= 1)
#pragma unroll
            for (int pr = 0; pr < 4; pr++) rs[pr] += __shfl_xor(rs[pr], xm, 64);
#pragma unroll
          for (int pr = 0; pr < 4; pr++) lsum[mi][pr] += rs[pr];
          char* pb = (char*)(&Ps[wid][0]);
#pragma unroll
          for (int kb = 0; kb < 4; kb++) {
            int col = kb * 16 + l15;
#pragma unroll
            for (int pr = 0; pr < 4; pr++) {
              int row = mi * 16 + l4 * 4 + pr;
              *(unsigned short*)(pb + row * 128 + (((col >> 3) ^ (row & 7)) * 16) +
                                 (col & 7) * 2) = f2bf(sc[mi][kb][pr]);
            }
          }
        }
        char* pb = (char*)(&Ps[wid][0]);
        __builtin_amdgcn_s_setprio(1);
#pragma unroll
        for (int ks = 0; ks < 2; ks++) {
          s16x8 pa[2];
#pragma unroll
          for (int mi = 0; mi < 2; mi++) {
            int row = mi * 16 + l15;
            int c = ks * 4 + l4;
            pa[mi] = *(const s16x8*)(pb + row * 128 + ((c ^ (row & 7)) * 16));
          }
#pragma unroll
          for (int nb = 0; nb < 8; nb++) {
            int r = nb * 16 + l15;
            int c = ks * 4 + l4;
            s16x8 vf = *(const s16x8*)((char*)Vs + r * 128 + ((c ^ (r & 7)) * 16));
            o[0][nb] = mfma_bf16(pa[0], vf, o[0][nb]);
            o[1][nb] = mfma_bf16(pa[1], vf, o[1][nb]);
          }
        }
        __builtin_amdgcn_s_setprio(0);
      }
      __syncthreads();
    }

#pragma unroll
    for (int mi = 0; mi < 2; mi++) {
      float inv[4];
#pragma unroll
      for (int pr = 0; pr < 4; pr++) inv[pr] = 1.f / lsum[mi][pr];
#pragma unroll
      for (int nb = 0; nb < 8; nb++) {
        int col = h * 128 + nb * 16 + l15;
#pragma unroll
        for (int pr = 0; pr < 4; pr++) {
          int q = qr0 + mi * 16 + l4 * 4 + pr;
          AO[(size_t)(q * 2 + b) * 4096 + col] = f2bf(o[mi][nb][pr] * inv[pr]);
        }
      }
    }
  }
}

// ---------------- launch ----------------
extern "C" void kernel_launch(void* const* d_in, const int* in_sizes, int n_in,
                              void* d_out, int out_size, void* d_ws, size_t ws_size,
                              hipStream_t stream) {
  const float* x = (const float*)d_in[0];
  const float* cosT = (const float*)d_in[2];
  const float* sinT = (const float*)d_in[3];
  const float* wq = (const float*)d_in[4];
  const float* wk = (const float*)d_in[5];
  const float* wv = (const float*)d_in[6];
  const float* wo = (const float*)d_in[7];
  float* out = (float*)d_out;

  char* ws = (char*)d_ws;
  unsigned short* xb = (unsigned short*)(ws);
  unsigned short* Qa = (unsigned short*)(ws + 33554432ull);
  unsigned short* Ka = (unsigned short*)(ws + 67108864ull);
  unsigned short* Vt = (unsigned short*)(ws + 75497472ull);
  unsigned short* AO = (unsigned short*)(ws + 83886080ull);
  unsigned short* wqb = (unsigned short*)(ws + 117440512ull);
  unsigned short* wkb = (unsigned short*)(ws + 150994944ull);
  unsigned short* wvb = (unsigned short*)(ws + 159383552ull);
  unsigned short* wob = (unsigned short*)(ws + 167772160ull);
  bool wcvt = ws_size >= 201326592ull;

  if (wcvt) {
    cvt_all<<<2048, 256, 0, stream>>>(x, wq, wk, wv, wo, xb, wqb, wkb, wvb, wob);
    gemm256<0><<<256, 512, 0, stream>>>(xb, wqb, Qa, cosT, sinT);
    gemm_kv<<<512, 256, 0, stream>>>(xb, wkb, wvb, Ka, Vt, cosT, sinT);
  } else {
    cvt_bf16<<<8192, 256, 0, stream>>>(x, xb, 2097152);
    gemm_bt<0, 4096, true><<<1024, 256, 0, stream>>>(xb, wq, nullptr, Qa, cosT, sinT);
    gemm_bt<1, 1024, true><<<256, 256, 0, stream>>>(xb, wk, nullptr, Ka, cosT, sinT);
    gemm_bt<2, 1024, true><<<256, 256, 0, stream>>>(xb, wv, nullptr, Vt, cosT, sinT);
  }
  attn_fwd<<<512, 256, 0, stream>>>(Qa, Ka, Vt, AO);
  if (wcvt) {
    gemm256<3><<<256, 512, 0, stream>>>(AO, wob, out, cosT, sinT);
  } else {
    gemm_bt<3, 4096, true><<<1024, 256, 0, stream>>>(AO, wo, nullptr, out, cosT, sinT);
  }
}

// Round 15
// 546.720 us; speedup vs baseline: 1.0754x; 1.0754x over previous
//
#include <hip/hip_runtime.h>

typedef __attribute__((ext_vector_type(8))) short s16x8;
typedef __attribute__((ext_vector_type(8))) __bf16 bf16x8;
typedef __attribute__((ext_vector_type(4))) float f32x4;

#define S_LEN 2048
#define KDIM  4096
// softmax scale * log2(e): (1/sqrt(128)) * 1.4426950408889634
#define CSOFT 0.12751743f

__device__ __forceinline__ unsigned short f2bf(float f) {
  unsigned u = __builtin_bit_cast(unsigned, f);
  u += 0x7fffu + ((u >> 16) & 1u);
  return (unsigned short)(u >> 16);
}

__device__ __forceinline__ f32x4 mfma_bf16(s16x8 a, s16x8 b, f32x4 c) {
  return __builtin_amdgcn_mfma_f32_16x16x32_bf16(
      __builtin_bit_cast(bf16x8, a), __builtin_bit_cast(bf16x8, b), c, 0, 0, 0);
}

// async global->LDS, 16B per lane. lds ptr must be wave-uniform; g is per-lane.
__device__ __forceinline__ void gload_lds16(const unsigned short* g, void* l) {
  __builtin_amdgcn_global_load_lds(
      (const __attribute__((address_space(1))) void*)g,
      (__attribute__((address_space(3))) void*)l, 16, 0, 0);
}

__device__ __forceinline__ void cvt8(const float* p, unsigned short* out) {
  f32x4 a = *(const f32x4*)(p);
  f32x4 b = *(const f32x4*)(p + 4);
  s16x8 v;
  v[0] = (short)f2bf(a[0]); v[1] = (short)f2bf(a[1]);
  v[2] = (short)f2bf(a[2]); v[3] = (short)f2bf(a[3]);
  v[4] = (short)f2bf(b[0]); v[5] = (short)f2bf(b[1]);
  v[6] = (short)f2bf(b[2]); v[7] = (short)f2bf(b[3]);
  *(s16x8*)(out) = v;
}

// ---------------- fp32 -> bf16 convert (fallback path) ----------------
__global__ void cvt_bf16(const float* __restrict__ in,
                         unsigned short* __restrict__ out, int n8) {
  int i = blockIdx.x * 256 + threadIdx.x;
  if (i >= n8) return;
  cvt8(in + (size_t)i * 8, out + (size_t)i * 8);
}

// fused 5-array convert: x 8192 | wq 8192 | wk 2048 | wv 2048 | wo 8192
// One chunk per block (R13-best): grid-stride variant regressed (R14, +41us).
__global__ void cvt_all(const float* __restrict__ x, const float* __restrict__ wq,
                        const float* __restrict__ wk, const float* __restrict__ wv,
                        const float* __restrict__ wo,
                        unsigned short* __restrict__ ox, unsigned short* __restrict__ oq,
                        unsigned short* __restrict__ ok, unsigned short* __restrict__ ov,
                        unsigned short* __restrict__ oo) {
  int blk = blockIdx.x;
  const float* src;
  unsigned short* dst;
  int i;
  if (blk < 8192) { src = x; dst = ox; i = blk; }
  else if (blk < 16384) { src = wq; dst = oq; i = blk - 8192; }
  else if (blk < 18432) { src = wk; dst = ok; i = blk - 16384; }
  else if (blk < 20480) { src = wv; dst = ov; i = blk - 18432; }
  else { src = wo; dst = oo; i = blk - 20480; }
  size_t idx = ((size_t)i * 256 + threadIdx.x) * 8;
  cvt8(src + idx, dst + idx);
}

// ====== 256x256 BK=64 8-wave pipelined GEMM, 3-phase/tile (6 barriers) ====
// XCD-locality: each XCD gets a 4rt x 8ct tile cluster.
// FROZEN at R11-best: 7 schedule variants (vmcnt depth 1-5, phase 3/4/8,
// asm ds_read) all land 31-33.5% MfmaUtil; do not re-enter.
template <int EPI>
__global__ __launch_bounds__(512, 1)
void gemm256(const unsigned short* __restrict__ A,
             const unsigned short* __restrict__ B,
             void* __restrict__ Out,
             const float* __restrict__ cosT,
             const float* __restrict__ sinT) {
  const int K = KDIM;
  __shared__ __align__(16) unsigned short As[2 * 2 * 8192];
  __shared__ __align__(16) unsigned short Bs[2 * 2 * 8192];

  const int tid = threadIdx.x;
  const int lane = tid & 63, wid = tid >> 6;
  const int l15 = lane & 15, l4 = lane >> 4;
  const int wr = wid >> 2, wc = wid & 3;

  int bid = blockIdx.x;
  const int xcd = bid & 7, ii = bid >> 3;
  const int rt = (xcd >> 1) * 4 + (ii >> 3);
  const int ct = (xcd & 1) * 8 + (ii & 7);
  const int row0 = rt * 256, col0 = ct * 256;

  const int ch0 = tid, ch1 = 512 + tid;
  const int sr0 = ch0 >> 3, u0 = (ch0 & 7) ^ (sr0 & 7);
  const int sr1 = ch1 >> 3, u1 = (ch1 & 7) ^ (sr1 & 7);
  const unsigned short* A0p = A + (size_t)(row0 + sr0) * K + u0 * 8;
  const unsigned short* A1p = A + (size_t)(row0 + sr1) * K + u1 * 8;
  const unsigned short* B0p = B + (size_t)(col0 + sr0) * K + u0 * 8;
  const unsigned short* B1p = B + (size_t)(col0 + sr1) * K + u1 * 8;

  const int rdo0 = l15 * 128 + ((l4 ^ (l15 & 7)) << 4);
  const int rdo1 = l15 * 128 + (((4 | l4) ^ (l15 & 7)) << 4);

  f32x4 acc[8][4];
#pragma unroll
  for (int m = 0; m < 8; m++)
#pragma unroll
    for (int n = 0; n < 4; n++) acc[m][n] = f32x4{0.f, 0.f, 0.f, 0.f};

  auto stageA = [&](int buf, int h, int kt) {
    char* d = (char*)As + buf * 32768 + h * 16384 + wid * 1024;
    size_t so = (size_t)h * 128 * K + kt;
    gload_lds16(A0p + so, d);
    gload_lds16(A1p + so, d + 8192);
  };
  auto stageB = [&](int buf, int h, int kt) {
    char* d = (char*)Bs + buf * 32768 + h * 16384 + wid * 1024;
    size_t so = (size_t)h * 128 * K + kt;
    gload_lds16(B0p + so, d);
    gload_lds16(B1p + so, d + 8192);
  };
  auto bar = [&]() { __builtin_amdgcn_s_barrier(); };
  auto quad = [&](const s16x8* ak0, const s16x8* ak1,
                  const s16x8* bk0, const s16x8* bk1, int mb, int nb) {
    __builtin_amdgcn_s_setprio(1);
#pragma unroll
    for (int mi = 0; mi < 4; mi++)
#pragma unroll
      for (int ni = 0; ni < 2; ni++) {
        acc[mb + mi][nb + ni] =
            mfma_bf16(ak0[mi], bk0[ni], acc[mb + mi][nb + ni]);
        acc[mb + mi][nb + ni] =
            mfma_bf16(ak1[mi], bk1[ni], acc[mb + mi][nb + ni]);
      }
    __builtin_amdgcn_s_setprio(0);
  };

  auto tile3 = [&](int buf, auto st1, auto st2, auto st3, int vmEnd) {
    const char* Ab = (const char*)As + buf * 32768 + wr * 16384;
    const char* Bb = (const char*)Bs + buf * 32768 + (wc >> 1) * 16384 +
                     (wc & 1) * 8192;
    s16x8 a0k0[4], a0k1[4], a1k0[4], a1k1[4];
    s16x8 b0k0[2], b0k1[2], b1k0[2], b1k1[2];

#pragma unroll
    for (int mi = 0; mi < 4; mi++) {
      a0k0[mi] = *(const s16x8*)(Ab + mi * 2048 + rdo0);
      a0k1[mi] = *(const s16x8*)(Ab + mi * 2048 + rdo1);
    }
#pragma unroll
    for (int ni = 0; ni < 2; ni++) {
      b0k0[ni] = *(const s16x8*)(Bb + ni * 2048 + rdo0);
      b0k1[ni] = *(const s16x8*)(Bb + ni * 2048 + rdo1);
    }
    st1();
    bar();
    quad(a0k0, a0k1, b0k0, b0k1, 0, 0);
    bar();

#pragma unroll
    for (int mi = 0; mi < 4; mi++) {
      a1k0[mi] = *(const s16x8*)(Ab + 8192 + mi * 2048 + rdo0);
      a1k1[mi] = *(const s16x8*)(Ab + 8192 + mi * 2048 + rdo1);
    }
    st2();
    bar();
    quad(a1k0, a1k1, b0k0, b0k1, 4, 0);
    bar();

#pragma unroll
    for (int ni = 0; ni < 2; ni++) {
      b1k0[ni] = *(const s16x8*)(Bb + 4096 + ni * 2048 + rdo0);
      b1k1[ni] = *(const s16x8*)(Bb + 4096 + ni * 2048 + rdo1);
    }
    st3();
    bar();
    quad(a0k0, a0k1, b1k0, b1k1, 0, 2);
    quad(a1k0, a1k1, b1k0, b1k1, 4, 2);
    if (vmEnd == 4) {
      asm volatile("s_waitcnt vmcnt(4)" ::: "memory");
    } else if (vmEnd == 0) {
      asm volatile("s_waitcnt vmcnt(0)" ::: "memory");
    }
    bar();
  };
  auto nop = [&]() {};

  stageA(0, 0, 0);
  stageA(0, 1, 0);
  stageB(0, 0, 0);
  stageB(0, 1, 0);
  stageA(1, 0, 64);
  stageA(1, 1, 64);
  asm volatile("s_waitcnt vmcnt(4)" ::: "memory");
  bar();

  for (int j = 0; j < 31; j++) {
    const int k1 = (2 * j + 1) * 64, k2 = (2 * j + 2) * 64,
              k3 = (2 * j + 3) * 64;
    tile3(0, [&] { stageB(1, 0, k1); }, [&] { stageB(1, 1, k1); },
          [&] { stageA(0, 0, k2); stageA(0, 1, k2); }, 4);
    tile3(1, [&] { stageB(0, 0, k2); }, [&] { stageB(0, 1, k2); },
          [&] { stageA(1, 0, k3); stageA(1, 1, k3); }, 4);
  }
  {
    const int k1 = 63 * 64;
    tile3(0, [&] { stageB(1, 0, k1); }, [&] { stageB(1, 1, k1); }, nop, 0);
    tile3(1, nop, nop, nop, -1);
  }

  // ---- epilogue ----
#pragma unroll
  for (int m = 0; m < 8; m++) {
#pragma unroll
    for (int n = 0; n < 4; n++) {
      f32x4 v = acc[m][n];
      int rowb = row0 + wr * 128 + m * 16 + l4 * 4;
      int col = col0 + wc * 64 + n * 16 + l15;
      if (EPI == 3) {
        float* o = (float*)Out;
#pragma unroll
        for (int r = 0; r < 4; r++) o[(size_t)(rowb + r) * 4096 + col] = v[r];
      } else {
        float vp[4];
#pragma unroll
        for (int r = 0; r < 4; r++) vp[r] = __shfl_xor(v[r], 1, 64);
        bool odd = lane & 1;
        int fi = (col & 127) >> 1;
#pragma unroll
        for (int r = 0; r < 4; r++) {
          int nn = rowb + r, s = nn >> 1;
          float c = cosT[s * 64 + fi], sn = sinT[s * 64 + fi];
          v[r] = odd ? (vp[r] * sn + v[r] * c) : (v[r] * c - vp[r] * sn);
        }
        unsigned short* o = (unsigned short*)Out;
        int hh = col >> 7, hd = col & 127;
#pragma unroll
        for (int r = 0; r < 4; r++) {
          int nn = rowb + r, s = nn >> 1, b = nn & 1;
          o[((size_t)(b * 32 + hh) * 2048 + s) * 128 + hd] = f2bf(v[r]);
        }
      }
    }
  }
}

// ====== merged K+V projection GEMM: 512 blocks, N=1024 each ======
// bid<256: K-task (RoPE, store [b][8][s][hd]); else V-task (store [b][8][hd][s])
// VGPR live set ~60 <= 128 cap at 4 waves/SIMD -> (256,4) is spill-free.
__global__ __launch_bounds__(256, 4)
void gemm_kv(const unsigned short* __restrict__ A,
             const unsigned short* __restrict__ Bk,
             const unsigned short* __restrict__ Bv,
             unsigned short* __restrict__ OutK,
             unsigned short* __restrict__ OutV,
             const float* __restrict__ cosT,
             const float* __restrict__ sinT) {
  const int K = KDIM;
  const int tid = threadIdx.x;
  const int lane = tid & 63, wid = tid >> 6;
  const int l15 = lane & 15, l4 = lane >> 4;
  const bool isV = blockIdx.x >= 256;
  const int lb = blockIdx.x & 255;
  const int ct = lb & 7, rt = lb >> 3;
  const int row0 = rt * 128, col0 = ct * 128;
  const int wr = wid >> 1, wc = wid & 1;
  const unsigned short* Bw = isV ? Bv : Bk;

  __shared__ __align__(16) unsigned short As[128 * 32];
  __shared__ __align__(16) unsigned short Bs[128 * 32];

  f32x4 acc[4][4];
#pragma unroll
  for (int i = 0; i < 4; i++)
#pragma unroll
    for (int j = 0; j < 4; j++) acc[i][j] = f32x4{0.f, 0.f, 0.f, 0.f};

  for (int kt = 0; kt < K; kt += 32) {
#pragma unroll
    for (int i = 0; i < 2; i++) {
      int j = wid * 2 + i;
      int ch = j * 64 + lane;
      int r = ch >> 2, c = ch & 3;
      int sc = c ^ ((r >> 1) & 3);
      gload_lds16(A + (size_t)(row0 + r) * K + kt + sc * 8, (char*)As + j * 1024);
      gload_lds16(Bw + (size_t)(col0 + r) * K + kt + sc * 8, (char*)Bs + j * 1024);
    }
    __syncthreads();

    s16x8 af[4], bfr[4];
#pragma unroll
    for (int mi = 0; mi < 4; mi++) {
      int r = wr * 64 + mi * 16 + l15;
      int sw = l4 ^ ((r >> 1) & 3);
      af[mi] = *(const s16x8*)((char*)As + r * 64 + sw * 16);
    }
#pragma unroll
    for (int ni = 0; ni < 4; ni++) {
      int r = wc * 64 + ni * 16 + l15;
      int sw = l4 ^ ((r >> 1) & 3);
      bfr[ni] = *(const s16x8*)((char*)Bs + r * 64 + sw * 16);
    }
#pragma unroll
    for (int mi = 0; mi < 4; mi++)
#pragma unroll
      for (int ni = 0; ni < 4; ni++)
        acc[mi][ni] = mfma_bf16(af[mi], bfr[ni], acc[mi][ni]);
    __syncthreads();
  }

#pragma unroll
  for (int mi = 0; mi < 4; mi++) {
#pragma unroll
    for (int ni = 0; ni < 4; ni++) {
      f32x4 v = acc[mi][ni];
      int rowb = row0 + wr * 64 + mi * 16 + l4 * 4;
      int col = col0 + wc * 64 + ni * 16 + l15;
      if (!isV) {  // RoPE for K
        float vp[4];
#pragma unroll
        for (int r = 0; r < 4; r++) vp[r] = __shfl_xor(v[r], 1, 64);
        bool odd = lane & 1;
        int fi = (col & 127) >> 1;
#pragma unroll
        for (int r = 0; r < 4; r++) {
          int n = rowb + r, s = n >> 1;
          float c = cosT[s * 64 + fi], sn = sinT[s * 64 + fi];
          v[r] = odd ? (vp[r] * sn + v[r] * c) : (v[r] * c - vp[r] * sn);
        }
        int hh = col >> 7, hd = col & 127;
#pragma unroll
        for (int r = 0; r < 4; r++) {
          int n = rowb + r, s = n >> 1, b = n & 1;
          OutK[((size_t)(b * 8 + hh) * 2048 + s) * 128 + hd] = f2bf(v[r]);
        }
      } else {
        int hh = col >> 7, hd = col & 127;
#pragma unroll
        for (int r = 0; r < 4; r++) {
          int n = rowb + r, s = n >> 1, b = n & 1;
          OutV[((size_t)(b * 8 + hh) * 128 + hd) * 2048 + s] = f2bf(v[r]);
        }
      }
    }
  }
}

// ---------------- GEMM: fallback-path template ----------------
template <int EPI, int N, bool B_FP32>
__global__ __launch_bounds__(256, 2)
void gemm_bt(const unsigned short* __restrict__ A,
             const float* __restrict__ Bw32,
             const unsigned short* __restrict__ Bw16,
             void* __restrict__ Out,
             const float* __restrict__ cosT,
             const float* __restrict__ sinT) {
  const int K = KDIM;
  const int tid = threadIdx.x;
  const int lane = tid & 63, wid = tid >> 6;
  const int l15 = lane & 15, l4 = lane >> 4;
  const int nct = N / 128;
  const int ct = blockIdx.x % nct, rt = blockIdx.x / nct;
  const int row0 = rt * 128, col0 = ct * 128;
  const int wr = wid >> 1, wc = wid & 1;

  __shared__ __align__(16) unsigned short As[128 * 32];
  __shared__ __align__(16) unsigned short Bs[128 * 32];

  f32x4 acc[4][4];
#pragma unroll
  for (int i = 0; i < 4; i++)
#pragma unroll
    for (int j = 0; j < 4; j++) acc[i][j] = f32x4{0.f, 0.f, 0.f, 0.f};

  for (int kt = 0; kt < K; kt += 32) {
#pragma unroll
    for (int i = 0; i < 2; i++) {
      int j = wid * 2 + i;
      int ch = j * 64 + lane;
      int r = ch >> 2, c = ch & 3;
      int sc = c ^ ((r >> 1) & 3);
      gload_lds16(A + (size_t)(row0 + r) * K + kt + sc * 8, (char*)As + j * 1024);
    }
    if (B_FP32) {
#pragma unroll
      for (int j = 0; j < 2; j++) {
        int ch = tid + 256 * j;
        int r = ch >> 2, c = ch & 3;
        const float* src = Bw32 + (size_t)(col0 + r) * K + kt + c * 8;
        f32x4 f0 = *(const f32x4*)(src);
        f32x4 f1 = *(const f32x4*)(src + 4);
        s16x8 v;
        v[0] = (short)f2bf(f0[0]); v[1] = (short)f2bf(f0[1]);
        v[2] = (short)f2bf(f0[2]); v[3] = (short)f2bf(f0[3]);
        v[4] = (short)f2bf(f1[0]); v[5] = (short)f2bf(f1[1]);
        v[6] = (short)f2bf(f1[2]); v[7] = (short)f2bf(f1[3]);
        int sw = c ^ ((r >> 1) & 3);
        *(s16x8*)((char*)Bs + r * 64 + sw * 16) = v;
      }
    } else {
#pragma unroll
      for (int i = 0; i < 2; i++) {
        int j = wid * 2 + i;
        int ch = j * 64 + lane;
        int r = ch >> 2, c = ch & 3;
        int sc = c ^ ((r >> 1) & 3);
        gload_lds16(Bw16 + (size_t)(col0 + r) * K + kt + sc * 8, (char*)Bs + j * 1024);
      }
    }
    __syncthreads();

    s16x8 af[4], bfr[4];
#pragma unroll
    for (int mi = 0; mi < 4; mi++) {
      int r = wr * 64 + mi * 16 + l15;
      int sw = l4 ^ ((r >> 1) & 3);
      af[mi] = *(const s16x8*)((char*)As + r * 64 + sw * 16);
    }
#pragma unroll
    for (int ni = 0; ni < 4; ni++) {
      int r = wc * 64 + ni * 16 + l15;
      int sw = l4 ^ ((r >> 1) & 3);
      bfr[ni] = *(const s16x8*)((char*)Bs + r * 64 + sw * 16);
    }
#pragma unroll
    for (int mi = 0; mi < 4; mi++)
#pragma unroll
      for (int ni = 0; ni < 4; ni++)
        acc[mi][ni] = mfma_bf16(af[mi], bfr[ni], acc[mi][ni]);
    __syncthreads();
  }

#pragma unroll
  for (int mi = 0; mi < 4; mi++) {
#pragma unroll
    for (int ni = 0; ni < 4; ni++) {
      f32x4 v = acc[mi][ni];
      int rowb = row0 + wr * 64 + mi * 16 + l4 * 4;
      int col = col0 + wc * 64 + ni * 16 + l15;
      if (EPI == 3) {
        float* o = (float*)Out;
#pragma unroll
        for (int r = 0; r < 4; r++) o[(size_t)(rowb + r) * 4096 + col] = v[r];
      } else {
        if (EPI != 2) {
          float vp[4];
#pragma unroll
          for (int r = 0; r < 4; r++) vp[r] = __shfl_xor(v[r], 1, 64);
          bool odd = lane & 1;
          int fi = (col & 127) >> 1;
#pragma unroll
          for (int r = 0; r < 4; r++) {
            int n = rowb + r, s = n >> 1;
            float c = cosT[s * 64 + fi], sn = sinT[s * 64 + fi];
            v[r] = odd ? (vp[r] * sn + v[r] * c) : (v[r] * c - vp[r] * sn);
          }
        }
        unsigned short* o = (unsigned short*)Out;
        int hh = col >> 7, hd = col & 127;
#pragma unroll
        for (int r = 0; r < 4; r++) {
          int n = rowb + r, s = n >> 1, b = n & 1;
          size_t idx;
          if (EPI == 0)      idx = ((size_t)(b * 32 + hh) * 2048 + s) * 128 + hd;
          else if (EPI == 1) idx = ((size_t)(b * 8 + hh) * 2048 + s) * 128 + hd;
          else               idx = ((size_t)(b * 8 + hh) * 128 + hd) * 2048 + s;
          o[idx] = f2bf(v[r]);
        }
      }
    }
  }
}

// ---------------- Flash attention (causal, GQA) — R11-exact (171us best) ---
__global__ __launch_bounds__(256, 2)
void attn_fwd(const unsigned short* __restrict__ Qa,
              const unsigned short* __restrict__ Ka,
              const unsigned short* __restrict__ Vt,
              unsigned short* __restrict__ AO) {
  int bid = blockIdx.x;
  int xcd = bid & 7, slot = bid >> 3;
  int grp = xcd + 8 * (slot >> 5);
  int idx = slot & 31;
  int b = grp >> 3, kvh = grp & 7;
  int pid = idx & 7;
  int h = kvh * 4 + ((idx >> 3) & 3);
  int tid = threadIdx.x, lane = tid & 63, wid = tid >> 6;
  int l15 = lane & 15, l4 = lane >> 4;

  __shared__ __align__(16) unsigned short Ks[64 * 128];
  __shared__ __align__(16) unsigned short Vs[128 * 64];
  __shared__ __align__(16) unsigned short Ps[4][32 * 64];

  const unsigned short* Qp = Qa + ((size_t)(b * 32 + h) * 2048) * 128;
  const unsigned short* Kp = Ka + ((size_t)(b * 8 + kvh) * 2048) * 128;
  const unsigned short* Vp = Vt + ((size_t)(b * 8 + kvh) * 128) * 2048;

  for (int half = 0; half < 2; half++) {
    int qt = half == 0 ? (7 - pid) : (8 + pid);
    int q0 = qt * 128, qr0 = q0 + wid * 32;

    s16x8 qf[2][4];
#pragma unroll
    for (int mi = 0; mi < 2; mi++)
#pragma unroll
      for (int ks = 0; ks < 4; ks++)
        qf[mi][ks] = *(const s16x8*)(Qp + (size_t)(qr0 + mi * 16 + l15) * 128 +
                                     ks * 32 + l4 * 8);

    f32x4 o[2][8];
#pragma unroll
    for (int mi = 0; mi < 2; mi++)
#pragma unroll
      for (int nb = 0; nb < 8; nb++) o[mi][nb] = f32x4{0.f, 0.f, 0.f, 0.f};
    float m[2][4], lsum[2][4];
#pragma unroll
    for (int mi = 0; mi < 2; mi++)
#pragma unroll
      for (int pr = 0; pr < 4; pr++) { m[mi][pr] = -1e30f; lsum[mi][pr] = 0.f; }

    int nt = q0 / 64 + 2;
    for (int t = 0; t < nt; t++) {
      int s0 = t * 64;
      const unsigned short* ktp = Kp + (size_t)s0 * 128;
#pragma unroll
      for (int i = 0; i < 4; i++) {
        int j = wid * 4 + i;
        int ch = j * 64 + lane;
        {
          int r = ch >> 4, cl = ch & 15;
          int sc = (cl & 8) | ((cl ^ (r & 7)) & 7);
          gload_lds16(ktp + r * 128 + sc * 8, (char*)Ks + j * 1024);
        }
        {
          int r = ch >> 3, p = ch & 7;
          int sc = p ^ (r & 7);
          gload_lds16(Vp + (size_t)r * 2048 + s0 + sc * 8, (char*)Vs + j * 1024);
        }
      }
      __syncthreads();

      if (s0 <= qr0 + 31) {
        f32x4 sc[2][4];
#pragma unroll
        for (int mi = 0; mi < 2; mi++)
#pragma unroll
          for (int kb = 0; kb < 4; kb++) sc[mi][kb] = f32x4{0.f, 0.f, 0.f, 0.f};
        __builtin_amdgcn_s_setprio(1);
#pragma unroll
        for (int kb = 0; kb < 4; kb++) {
          int r = kb * 16 + l15;
#pragma unroll
          for (int ks = 0; ks < 4; ks++) {
            int c = ks * 4 + l4;
            int sw = (c & 8) | ((c ^ (r & 7)) & 7);
            s16x8 kf = *(const s16x8*)((char*)Ks + r * 256 + sw * 16);
            sc[0][kb] = mfma_bf16(qf[0][ks], kf, sc[0][kb]);
            sc[1][kb] = mfma_bf16(qf[1][ks], kf, sc[1][kb]);
          }
        }
        __builtin_amdgcn_s_setprio(0);
        bool needmask = (s0 + 63) > qr0;
#pragma unroll
        for (int mi = 0; mi < 2; mi++) {
          if (needmask) {
#pragma unroll
            for (int kb = 0; kb < 4; kb++) {
              int kg = s0 + kb * 16 + l15;
#pragma unroll
              for (int pr = 0; pr < 4; pr++) {
                int qg = qr0 + mi * 16 + l4 * 4 + pr;
                if (kg > qg) sc[mi][kb][pr] = -1e30f;
              }
            }
          }
          float rm[4];
#pragma unroll
          for (int pr = 0; pr < 4; pr++)
            rm[pr] = fmaxf(fmaxf(sc[mi][0][pr], sc[mi][1][pr]),
                           fmaxf(sc[mi][2][pr], sc[mi][3][pr]));
#pragma unroll
          for (int xm = 1; xm <= 8; xm <<= 1)
#pragma unroll
            for (int pr = 0; pr < 4; pr++)
              rm[pr] = fmaxf(rm[pr], __shfl_xor(rm[pr], xm, 64));
          bool grow = false;
#pragma unroll
          for (int pr = 0; pr < 4; pr++)
            grow = grow || ((rm[pr] - m[mi][pr]) * CSOFT > 8.f);
          if (__any(grow)) {
            float fac[4];
#pragma unroll
            for (int pr = 0; pr < 4; pr++) {
              float nm = fmaxf(m[mi][pr], rm[pr]);
              fac[pr] = __builtin_amdgcn_exp2f((m[mi][pr] - nm) * CSOFT);
              m[mi][pr] = nm;
              lsum[mi][pr] *= fac[pr];
            }
#pragma unroll
            for (int nb = 0; nb < 8; nb++)
#pragma unroll
              for (int pr = 0; pr < 4; pr++) o[mi][nb][pr] *= fac[pr];
          }
          float rs[4] = {0.f, 0.f, 0.f, 0.f};
#pragma unroll
          for (int kb = 0; kb < 4; kb++)
#pragma unroll
            for (int pr = 0; pr < 4; pr++) {
              float p = __builtin_amdgcn_exp2f((sc[mi][kb][pr] - m[mi][pr]) * CSOFT);
              sc[mi][kb][pr] = p;
              rs[pr] += p;
            }
#pragma unroll
          for (int xm = 1; xm <= 8; xm <<= 1)
#pragma unroll
            for (int pr = 0; pr < 4; pr++) rs[pr] += __shfl_xor(rs[pr], xm, 64);
#pragma unroll
          for (int pr = 0; pr < 4; pr++) lsum[mi][pr] += rs[pr];
          char* pb = (char*)(&Ps[wid][0]);
#pragma unroll
          for (int kb = 0; kb < 4; kb++) {
            int col = kb * 16 + l15;
#pragma unroll
            for (int pr = 0; pr < 4; pr++) {
              int row = mi * 16 + l4 * 4 + pr;
              *(unsigned short*)(pb + row * 128 + (((col >> 3) ^ (row & 7)) * 16) +
                                 (col & 7) * 2) = f2bf(sc[mi][kb][pr]);
            }
          }
        }
        char* pb = (char*)(&Ps[wid][0]);
        __builtin_amdgcn_s_setprio(1);
#pragma unroll
        for (int ks = 0; ks < 2; ks++) {
          s16x8 pa[2];
#pragma unroll
          for (int mi = 0; mi < 2; mi++) {
            int row = mi * 16 + l15;
            int c = ks * 4 + l4;
            pa[mi] = *(const s16x8*)(pb + row * 128 + ((c ^ (row & 7)) * 16));
          }
#pragma unroll
          for (int nb = 0; nb < 8; nb++) {
            int r = nb * 16 + l15;
            int c = ks * 4 + l4;
            s16x8 vf = *(const s16x8*)((char*)Vs + r * 128 + ((c ^ (r & 7)) * 16));
            o[0][nb] = mfma_bf16(pa[0], vf, o[0][nb]);
            o[1][nb] = mfma_bf16(pa[1], vf, o[1][nb]);
          }
        }
        __builtin_amdgcn_s_setprio(0);
      }
      __syncthreads();
    }

#pragma unroll
    for (int mi = 0; mi < 2; mi++) {
      float inv[4];
#pragma unroll
      for (int pr = 0; pr < 4; pr++) inv[pr] = 1.f / lsum[mi][pr];
#pragma unroll
      for (int nb = 0; nb < 8; nb++) {
        int col = h * 128 + nb * 16 + l15;
#pragma unroll
        for (int pr = 0; pr < 4; pr++) {
          int q = qr0 + mi * 16 + l4 * 4 + pr;
          AO[(size_t)(q * 2 + b) * 4096 + col] = f2bf(o[mi][nb][pr] * inv[pr]);
        }
      }
    }
  }
}

// ---------------- launch ----------------
extern "C" void kernel_launch(void* const* d_in, const int* in_sizes, int n_in,
                              void* d_out, int out_size, void* d_ws, size_t ws_size,
                              hipStream_t stream) {
  const float* x = (const float*)d_in[0];
  const float* cosT = (const float*)d_in[2];
  const float* sinT = (const float*)d_in[3];
  const float* wq = (const float*)d_in[4];
  const float* wk = (const float*)d_in[5];
  const float* wv = (const float*)d_in[6];
  const float* wo = (const float*)d_in[7];
  float* out = (float*)d_out;

  char* ws = (char*)d_ws;
  unsigned short* xb = (unsigned short*)(ws);
  unsigned short* Qa = (unsigned short*)(ws + 33554432ull);
  unsigned short* Ka = (unsigned short*)(ws + 67108864ull);
  unsigned short* Vt = (unsigned short*)(ws + 75497472ull);
  unsigned short* AO = (unsigned short*)(ws + 83886080ull);
  unsigned short* wqb = (unsigned short*)(ws + 117440512ull);
  unsigned short* wkb = (unsigned short*)(ws + 150994944ull);
  unsigned short* wvb = (unsigned short*)(ws + 159383552ull);
  unsigned short* wob = (unsigned short*)(ws + 167772160ull);
  bool wcvt = ws_size >= 201326592ull;

  if (wcvt) {
    cvt_all<<<28672, 256, 0, stream>>>(x, wq, wk, wv, wo, xb, wqb, wkb, wvb, wob);
    gemm256<0><<<256, 512, 0, stream>>>(xb, wqb, Qa, cosT, sinT);
    gemm_kv<<<512, 256, 0, stream>>>(xb, wkb, wvb, Ka, Vt, cosT, sinT);
  } else {
    cvt_bf16<<<8192, 256, 0, stream>>>(x, xb, 2097152);
    gemm_bt<0, 4096, true><<<1024, 256, 0, stream>>>(xb, wq, nullptr, Qa, cosT, sinT);
    gemm_bt<1, 1024, true><<<256, 256, 0, stream>>>(xb, wk, nullptr, Ka, cosT, sinT);
    gemm_bt<2, 1024, true><<<256, 256, 0, stream>>>(xb, wv, nullptr, Vt, cosT, sinT);
  }
  attn_fwd<<<512, 256, 0, stream>>>(Qa, Ka, Vt, AO);
  if (wcvt) {
    gemm256<3><<<256, 512, 0, stream>>>(AO, wob, out, cosT, sinT);
  } else {
    gemm_bt<3, 4096, true><<<1024, 256, 0, stream>>>(AO, wo, nullptr, out, cosT, sinT);
  }
}